// Round 1
// baseline (93.869 us; speedup 1.0000x reference)
//
#include <hip/hip_runtime.h>

// AdaptiveRankingLoss, N=8192, fp32 in / scalar fp32 out.
//
// Symmetry: term(i,j) == term(j,i) and diagonal is masked (tdiff==0), so
// sum over ALL ordered pairs divided by count over all ordered pairs equals
// the reference's upper-triangular mean exactly.

constexpr int BLOCK = 256;   // one i per thread
constexpr int TJ    = 256;   // j-tile staged in LDS

__global__ __launch_bounds__(BLOCK) void arl_pair_kernel(
    const float* __restrict__ pred, const float* __restrict__ targ,
    const float* __restrict__ unc, int n,
    double* __restrict__ loss_out, unsigned long long* __restrict__ cnt_out)
{
    __shared__ float sp[TJ], st[TJ], su[TJ];
    const int tid = threadIdx.x;
    const int i   = blockIdx.x * BLOCK + tid;
    const int j0  = blockIdx.y * TJ;

    {
        const int j = j0 + tid;
        const bool v = j < n;
        sp[tid] = v ? pred[j] : 0.0f;
        st[tid] = v ? targ[j] : 0.0f;
        su[tid] = v ? unc[j]  : 0.0f;
    }
    __syncthreads();

    float acc = 0.0f;
    unsigned cnt = 0;

    if (i < n) {
        const float pi  = pred[i];
        const float ti  = targ[i];
        const float ui1 = 1.0f + unc[i];
        const int jmax = (n - j0 < TJ) ? (n - j0) : TJ;
        #pragma unroll 8
        for (int jj = 0; jj < jmax; ++jj) {
            const float tj = st[jj];
            const float pj = sp[jj];
            const float uj = su[jj];
            const float tdiff = ti - tj;
            const float pdiff = pi - pj;
            const float a      = fabsf(tdiff);
            const float margin = 0.1f * fminf(fmaxf(a, 0.1f), 1.0f);
            // sign(tdiff)*pdiff for tdiff != 0 (tdiff==0 is masked anyway)
            const float spd = (tdiff < 0.0f) ? -pdiff : pdiff;
            const float h   = fmaxf(margin - spd, 0.0f);
            const float w   = __builtin_amdgcn_rcpf(ui1 + uj); // 1/(1+u_i+u_j), ~1ulp
            if (tdiff != 0.0f) {
                acc += w * h;
                cnt += 1u;
            }
        }
    }

    // wave (64-lane) reduction
    int icnt = (int)cnt;
    for (int off = 32; off > 0; off >>= 1) {
        acc  += __shfl_down(acc, off);
        icnt += __shfl_down(icnt, off);
    }

    __shared__ float    wacc[BLOCK / 64];
    __shared__ unsigned wcnt[BLOCK / 64];
    const int lane = tid & 63;
    const int wid  = tid >> 6;
    if (lane == 0) { wacc[wid] = acc; wcnt[wid] = (unsigned)icnt; }
    __syncthreads();

    if (tid == 0) {
        float a2 = 0.0f;
        unsigned long long c2 = 0;
        #pragma unroll
        for (int w = 0; w < BLOCK / 64; ++w) { a2 += wacc[w]; c2 += wcnt[w]; }
        atomicAdd(loss_out, (double)a2);
        atomicAdd(cnt_out, c2);
    }
}

__global__ void arl_finalize(const double* __restrict__ loss,
                             const unsigned long long* __restrict__ cnt,
                             float* __restrict__ out)
{
    const unsigned long long c = *cnt;
    const double denom = (double)(c ? c : 1ull);
    out[0] = (float)(*loss / denom);
}

extern "C" void kernel_launch(void* const* d_in, const int* in_sizes, int n_in,
                              void* d_out, int out_size, void* d_ws, size_t ws_size,
                              hipStream_t stream) {
    const float* pred = (const float*)d_in[0];
    const float* targ = (const float*)d_in[1];
    const float* unc  = (const float*)d_in[2];
    const int n = in_sizes[0];

    double* loss = (double*)d_ws;
    unsigned long long* cnt = (unsigned long long*)((char*)d_ws + 8);

    hipMemsetAsync(d_ws, 0, 16, stream);  // ws is poisoned 0xAA before every call

    dim3 grid((n + BLOCK - 1) / BLOCK, (n + TJ - 1) / TJ);
    arl_pair_kernel<<<grid, BLOCK, 0, stream>>>(pred, targ, unc, n, loss, cnt);
    arl_finalize<<<1, 1, 0, stream>>>(loss, cnt, (float*)d_out);
}